// Round 19
// baseline (540.752 us; speedup 1.0000x reference)
//
#include <hip/hip_runtime.h>
#include <hip/hip_bf16.h>
#include <cstdint>

// Problem constants (match setup_inputs)
constexpr int B  = 2;
constexpr int L  = 2048;
constexpr int S  = 2048;
constexpr int DM = 1024;
constexpr int H  = 16;
constexpr int R  = 32;     // rank
constexpr int DH = 64;     // head dim
constexpr int TOPK = 32;
constexpr int SELCAP = 36;
constexpr float SCALE = 0.17677669529663687f; // 1/sqrt(32)

// MEASURED (R4-R18): VGPR cap = LDS-implied occupancy; LICM -> opaque-zero
// asm. R17: fragment-ordered K -> coalesced MFMA loads. R18: candidate-pruned
// exact top-k (attn 234us). R19: 16 REAL rows/block (was 8 + 8 zero-pad) ->
// K L2 traffic per row halves, MFMA M-waste gone. 134KB LDS -> 1 blk/CU ->
// 256-VGPR cap (no spill). Per-row arithmetic identical -> bit-identical.

using short8 = __attribute__((ext_vector_type(8))) short;
using f32x4  = __attribute__((ext_vector_type(4))) float;

__device__ __forceinline__ unsigned short bf16_rne(float x) {
    unsigned int u = __float_as_uint(x);
    unsigned int r = u + 0x7FFFu + ((u >> 16) & 1u);
    return (unsigned short)(r >> 16);
}
__device__ __forceinline__ float bf16_up(unsigned short h) {
    return __uint_as_float((unsigned int)h << 16);
}
__device__ __forceinline__ float inv_sortable(unsigned int uu) {
    unsigned int sg2 = (unsigned int)(((int)uu) >> 31);
    return __uint_as_float(uu ^ (0x80000000u | ~sg2));
}

// ---------------------------------------------------------------------------
// Merged Q/K projection. z=0: Q -> fp32 Qp (pre-scaled). z=1: K -> 3-term
// bf16 splits in MFMA-fragment order (R17-proven).
// ---------------------------------------------------------------------------
__global__ __launch_bounds__(256, 2)
void qk_proj(const float* __restrict__ Aq, const float* __restrict__ Wq_,
             const float* __restrict__ bq_, float* __restrict__ Qp,
             const float* __restrict__ Ak, const float* __restrict__ Wk_,
             const float* __restrict__ bk_, unsigned short* __restrict__ Kf,
             int M, int N, int K)
{
    const int z = blockIdx.z;
    const float* A    = z ? Ak  : Aq;
    const float* W    = z ? Wk_ : Wq_;
    const float* bias = z ? bk_ : bq_;

    __shared__ float As[16][136];
    __shared__ float Ws[16][132];

    const int t  = threadIdx.x;
    const int tx = t & 15;
    const int ty = t >> 4;
    const int m0 = blockIdx.y * 128;
    const int n0 = blockIdx.x * 128;

    float acc[8][8];
#pragma unroll
    for (int i = 0; i < 8; ++i)
#pragma unroll
        for (int j = 0; j < 8; ++j) acc[i][j] = 0.f;

    for (int kb = 0; kb < K; kb += 16) {
        __syncthreads();
#pragma unroll
        for (int it = 0; it < 2; ++it) {
            int f4  = t + it * 256;
            int row = f4 >> 2;
            int cg  = (f4 & 3) * 4;
            float4 av = *(const float4*)&A[(size_t)(m0 + row) * K + kb + cg];
            As[cg + 0][row] = av.x;
            As[cg + 1][row] = av.y;
            As[cg + 2][row] = av.z;
            As[cg + 3][row] = av.w;
        }
#pragma unroll
        for (int it = 0; it < 2; ++it) {
            int f4 = t + it * 256;
            int kk = f4 >> 5;
            int cb = (f4 & 31) * 4;
            *(float4*)&Ws[kk][cb] = *(const float4*)&W[(size_t)(kb + kk) * N + n0 + cb];
        }
        __syncthreads();
#pragma unroll
        for (int kk = 0; kk < 16; ++kk) {
            float4 a0 = *(const float4*)&As[kk][ty * 8];
            float4 a1 = *(const float4*)&As[kk][ty * 8 + 4];
            float4 w0 = *(const float4*)&Ws[kk][tx * 8];
            float4 w1 = *(const float4*)&Ws[kk][tx * 8 + 4];
            float a[8] = {a0.x, a0.y, a0.z, a0.w, a1.x, a1.y, a1.z, a1.w};
            float w[8] = {w0.x, w0.y, w0.z, w0.w, w1.x, w1.y, w1.z, w1.w};
#pragma unroll
            for (int i = 0; i < 8; ++i)
#pragma unroll
                for (int j = 0; j < 8; ++j)
                    acc[i][j] = fmaf(a[i], w[j], acc[i][j]);
        }
    }

    float4 b0 = *(const float4*)&bias[n0 + tx * 8];
    float4 b1 = *(const float4*)&bias[n0 + tx * 8 + 4];

    if (z == 0) {
#pragma unroll
        for (int i = 0; i < 8; ++i) {
            float4 o0 = make_float4((acc[i][0] + b0.x) * SCALE, (acc[i][1] + b0.y) * SCALE,
                                    (acc[i][2] + b0.z) * SCALE, (acc[i][3] + b0.w) * SCALE);
            float4 o1 = make_float4((acc[i][4] + b1.x) * SCALE, (acc[i][5] + b1.y) * SCALE,
                                    (acc[i][6] + b1.z) * SCALE, (acc[i][7] + b1.w) * SCALE);
            size_t off = (size_t)(m0 + ty * 8 + i) * N + n0 + tx * 8;
            *(float4*)&Qp[off]     = o0;
            *(float4*)&Qp[off + 4] = o1;
        }
    } else {
        float bb[8] = {b0.x, b0.y, b0.z, b0.w, b1.x, b1.y, b1.z, b1.w};
        const int h2 = (n0 + tx * 8) >> 5;
        const int l4 = ((n0 + tx * 8) & 31) >> 3;
#pragma unroll
        for (int i = 0; i < 8; ++i) {
            unsigned short hh[8], mm[8], ll[8];
#pragma unroll
            for (int j = 0; j < 8; ++j) {
                float x = acc[i][j] + bb[j];
                hh[j] = bf16_rne(x);
                float xr = x - bf16_up(hh[j]);
                mm[j] = bf16_rne(xr);
                ll[j] = bf16_rne(xr - bf16_up(mm[j]));
            }
            const int grow = m0 + ty * 8 + i;
            const int bat  = grow >> 11;
            const int key  = grow & 2047;
            const int T    = key >> 4;
            const int l15  = key & 15;
            const size_t base = (((size_t)(bat * H + h2) * 128 + T) * 1536)
                              + (size_t)(l4 * 16 + l15) * 8;
            ushort4 h0v = {hh[0], hh[1], hh[2], hh[3]}, h1v = {hh[4], hh[5], hh[6], hh[7]};
            ushort4 m0v = {mm[0], mm[1], mm[2], mm[3]}, m1v = {mm[4], mm[5], mm[6], mm[7]};
            ushort4 l0v = {ll[0], ll[1], ll[2], ll[3]}, l1v = {ll[4], ll[5], ll[6], ll[7]};
            *(ushort4*)&Kf[base]            = h0v;
            *(ushort4*)&Kf[base + 4]        = h1v;
            *(ushort4*)&Kf[base + 512]      = m0v;
            *(ushort4*)&Kf[base + 512 + 4]  = m1v;
            *(ushort4*)&Kf[base + 1024]     = l0v;
            *(ushort4*)&Kf[base + 1024 + 4] = l1v;
        }
    }
}

// ---------------------------------------------------------------------------
// Dual transpose + split (R12-proven).
// ---------------------------------------------------------------------------
__global__ __launch_bounds__(256)
void transpose_split_dual(const float* __restrict__ Wv_, unsigned short* __restrict__ VhT,
                          unsigned short* __restrict__ VlT,
                          const float* __restrict__ Wo_, unsigned short* __restrict__ OhT,
                          unsigned short* __restrict__ OlT, int N, int K)
{
    const int z = blockIdx.z;
    const float* W = z ? Wo_ : Wv_;
    unsigned short* Th = z ? OhT : VhT;
    unsigned short* Tl = z ? OlT : VlT;

    __shared__ float tile[32][33];
    const int n0 = blockIdx.x * 32;
    const int k0 = blockIdx.y * 32;
    const int tx = threadIdx.x & 31;
    const int ty = threadIdx.x >> 5;

#pragma unroll
    for (int i = ty; i < 32; i += 8)
        tile[i][tx] = W[(size_t)(k0 + i) * N + n0 + tx];
    __syncthreads();
#pragma unroll
    for (int i = ty; i < 32; i += 8) {
        float x = tile[tx][i];
        unsigned short h = bf16_rne(x);
        float hf = bf16_up(h);
        unsigned short l = bf16_rne(x - hf);
        Th[(size_t)(n0 + i) * K + k0 + tx] = h;
        Tl[(size_t)(n0 + i) * K + k0 + tx] = l;
    }
}

// ---------------------------------------------------------------------------
// Split-bf16 MFMA GEMM (R11-proven).
// ---------------------------------------------------------------------------
__global__ __launch_bounds__(256, 1)
void gemm_mfma_split(const float* __restrict__ A, const unsigned short* __restrict__ Bh,
                     const unsigned short* __restrict__ Bl, const float* __restrict__ bias,
                     float* __restrict__ C, int M, int N, int K)
{
    constexpr int LDT = 56;
    __shared__ unsigned short Ah[128 * LDT];
    __shared__ unsigned short Al[128 * LDT];
    __shared__ unsigned short Wh[128 * LDT];
    __shared__ unsigned short Wl[128 * LDT];

    const int t    = threadIdx.x;
    const int lane = t & 63;
    const int w    = t >> 6;
    const int wr   = w >> 1;
    const int wc   = w & 1;
    const int l15  = lane & 15;
    const int l4   = lane >> 4;
    const int m0   = blockIdx.y * 128;
    const int n0   = blockIdx.x * 128;

    f32x4 acc[4][4];
#pragma unroll
    for (int m = 0; m < 4; ++m)
#pragma unroll
        for (int n = 0; n < 4; ++n) {
            f32x4 z = {0.f, 0.f, 0.f, 0.f};
            acc[m][n] = z;
        }

#pragma unroll 1
    for (int kb = 0; kb < K; kb += 32) {
        __syncthreads();
#pragma unroll
        for (int it = 0; it < 4; ++it) {
            int f   = t + it * 256;
            int row = f >> 3;
            int kg  = (f & 7) * 4;
            float4 av = *(const float4*)&A[(size_t)(m0 + row) * K + kb + kg];
            ushort4 hv, lv;
            hv.x = bf16_rne(av.x); lv.x = bf16_rne(av.x - bf16_up(hv.x));
            hv.y = bf16_rne(av.y); lv.y = bf16_rne(av.y - bf16_up(hv.y));
            hv.z = bf16_rne(av.z); lv.z = bf16_rne(av.z - bf16_up(hv.z));
            hv.w = bf16_rne(av.w); lv.w = bf16_rne(av.w - bf16_up(hv.w));
            *(ushort4*)&Ah[row * LDT + kg] = hv;
            *(ushort4*)&Al[row * LDT + kg] = lv;
            ushort4 bh4 = *(const ushort4*)&Bh[(size_t)(n0 + row) * K + kb + kg];
            ushort4 bl4 = *(const ushort4*)&Bl[(size_t)(n0 + row) * K + kb + kg];
            *(ushort4*)&Wh[row * LDT + kg] = bh4;
            *(ushort4*)&Wl[row * LDT + kg] = bl4;
        }
        __syncthreads();

        short8 ah[4], al[4], bh[4], bl[4];
#pragma unroll
        for (int m = 0; m < 4; ++m) {
            int row = wr * 64 + m * 16 + l15;
            ah[m] = *(short8*)&Ah[row * LDT + l4 * 8];
            al[m] = *(short8*)&Al[row * LDT + l4 * 8];
        }
#pragma unroll
        for (int n = 0; n < 4; ++n) {
            int col = wc * 64 + n * 16 + l15;
            bh[n] = *(short8*)&Wh[col * LDT + l4 * 8];
            bl[n] = *(short8*)&Wl[col * LDT + l4 * 8];
        }
#pragma unroll
        for (int m = 0; m < 4; ++m)
#pragma unroll
            for (int n = 0; n < 4; ++n)
                acc[m][n] = __builtin_amdgcn_mfma_f32_16x16x32_bf16(ah[m], bh[n], acc[m][n], 0, 0, 0);
#pragma unroll
        for (int m = 0; m < 4; ++m)
#pragma unroll
            for (int n = 0; n < 4; ++n)
                acc[m][n] = __builtin_amdgcn_mfma_f32_16x16x32_bf16(ah[m], bl[n], acc[m][n], 0, 0, 0);
#pragma unroll
        for (int m = 0; m < 4; ++m)
#pragma unroll
            for (int n = 0; n < 4; ++n)
                acc[m][n] = __builtin_amdgcn_mfma_f32_16x16x32_bf16(al[m], bh[n], acc[m][n], 0, 0, 0);
    }

#pragma unroll
    for (int m = 0; m < 4; ++m) {
        int row = m0 + wr * 64 + m * 16 + l4 * 4;
#pragma unroll
        for (int n = 0; n < 4; ++n) {
            int col = n0 + wc * 64 + n * 16 + l15;
            float bv = bias[col];
#pragma unroll
            for (int r = 0; r < 4; ++r)
                C[(size_t)(row + r) * N + col] = acc[m][n][r] + bv;
        }
    }
}

// ---------------------------------------------------------------------------
// Fused MFMA score + candidate-pruned exact top-k + softmax + PV gather.
// v19: 16 REAL q-rows per block (no M padding). Score LDS [16][2049] (stride
// 2049 -> C-writes bank-conflict-free: bank=(row+col)%32, l4 spreads rows).
// Each wave: same 96 MFMA / 48 fragment loads as R18 but all 16 rows real.
// Selection (R18 code): wave wv handles rows {2wv, 2wv+1} sequentially.
// Per-row arithmetic identical to R18 -> bit-identical output.
// ---------------------------------------------------------------------------
__global__ __launch_bounds__(512, 1)
void score_select_gather(const float* __restrict__ Qp,
                         const unsigned short* __restrict__ Kf,
                         const float* __restrict__ Vp, float* __restrict__ Oh)
{
    constexpr int LDS_STRIDE = 2049;
    __shared__ float sclds[16][LDS_STRIDE];    // 131136 B
    __shared__ unsigned short Qs[3][16][32];   // 3 KB

    const int t    = threadIdx.x;
    const int lane = t & 63;
    const int wv   = t >> 6;            // 0..7

    const int wgid = blockIdx.x;             // 0..4095
    const int xcd  = wgid & 7;
    const int jj   = wgid >> 3;              // 0..511
    const int bh_  = xcd + 8 * (jj >> 7);    // 0..31
    const int tile = jj & 127;
    const int b    = bh_ >> 4;
    const int h    = bh_ & 15;
    const int lbase = tile * 16;

    // stage + split Q: 16 rows x 32 (all real)
    {
        int row = t >> 5;       // 0..15
        int col = t & 31;
        float x = Qp[(size_t)(b * L + lbase + row) * (H * R) + h * R + col];
        unsigned short hh = bf16_rne(x);
        float xr = x - bf16_up(hh);
        unsigned short mm = bf16_rne(xr);
        unsigned short ll = bf16_rne(xr - bf16_up(mm));
        Qs[0][row][col] = hh;
        Qs[1][row][col] = mm;
        Qs[2][row][col] = ll;
    }
    __syncthreads();

    const int l15 = lane & 15;
    const int l4  = lane >> 4;

    const short8 ah = *(const short8*)&Qs[0][l15][l4 * 8];
    const short8 am = *(const short8*)&Qs[1][l15][l4 * 8];
    const short8 al = *(const short8*)&Qs[2][l15][l4 * 8];

    const unsigned short* kfb = Kf + (size_t)bh_ * 128 * 1536;

#pragma unroll 1
    for (int p = 0; p < 8; ++p) {
        const int T0 = wv * 16 + p * 2;
        const unsigned short* t0 = kfb + (size_t)T0 * 1536 + lane * 8;
        const unsigned short* t1 = t0 + 1536;
        const short8 bh0 = *(const short8*)(t0);
        const short8 bm0 = *(const short8*)(t0 + 512);
        const short8 bl0 = *(const short8*)(t0 + 1024);
        const short8 bh1 = *(const short8*)(t1);
        const short8 bm1 = *(const short8*)(t1 + 512);
        const short8 bl1 = *(const short8*)(t1 + 1024);

        f32x4 acc0 = {0.f, 0.f, 0.f, 0.f};
        f32x4 acc1 = {0.f, 0.f, 0.f, 0.f};
        acc0 = __builtin_amdgcn_mfma_f32_16x16x32_bf16(ah, bh0, acc0, 0, 0, 0);
        acc1 = __builtin_amdgcn_mfma_f32_16x16x32_bf16(ah, bh1, acc1, 0, 0, 0);
        acc0 = __builtin_amdgcn_mfma_f32_16x16x32_bf16(ah, bm0, acc0, 0, 0, 0);
        acc1 = __builtin_amdgcn_mfma_f32_16x16x32_bf16(ah, bm1, acc1, 0, 0, 0);
        acc0 = __builtin_amdgcn_mfma_f32_16x16x32_bf16(am, bh0, acc0, 0, 0, 0);
        acc1 = __builtin_amdgcn_mfma_f32_16x16x32_bf16(am, bh1, acc1, 0, 0, 0);
        acc0 = __builtin_amdgcn_mfma_f32_16x16x32_bf16(am, bm0, acc0, 0, 0, 0);
        acc1 = __builtin_amdgcn_mfma_f32_16x16x32_bf16(am, bm1, acc1, 0, 0, 0);
        acc0 = __builtin_amdgcn_mfma_f32_16x16x32_bf16(ah, bl0, acc0, 0, 0, 0);
        acc1 = __builtin_amdgcn_mfma_f32_16x16x32_bf16(ah, bl1, acc1, 0, 0, 0);
        acc0 = __builtin_amdgcn_mfma_f32_16x16x32_bf16(al, bh0, acc0, 0, 0, 0);
        acc1 = __builtin_amdgcn_mfma_f32_16x16x32_bf16(al, bh1, acc1, 0, 0, 0);

        // all 16 C rows real: row = l4*4 + r
        const int kc0 = wv * 256 + p * 32 + l15;
#pragma unroll
        for (int r = 0; r < 4; ++r) {
            sclds[l4 * 4 + r][kc0]      = acc0[r];
            sclds[l4 * 4 + r][kc0 + 16] = acc1[r];
        }
    }

    __syncthreads();

    const unsigned long long lanelt = (1ull << lane) - 1ull;

#pragma unroll 1
    for (int rr = 0; rr < 2; ++rr) {
        const int r = wv * 2 + rr;

        unsigned int u[32];
#pragma unroll
        for (int j = 0; j < 32; ++j) {
            unsigned int bb  = __float_as_uint(sclds[r][j * 64 + lane]);
            unsigned int sgn = (unsigned int)(((int)bb) >> 31);
            u[j] = bb ^ (sgn | 0x80000000u);
        }

        unsigned int lmax = u[0];
#pragma unroll
        for (int j = 1; j < 32; ++j) lmax = lmax > u[j] ? lmax : u[j];
        unsigned int umx = lmax;
#pragma unroll
        for (int off = 32; off >= 1; off >>= 1) {
            unsigned int o = (unsigned int)__shfl_xor((int)umx, off, 64);
            umx = umx > o ? umx : o;
        }
        const float mx = inv_sortable(umx);

        unsigned int PM = 0;
        for (int bit = 31; bit >= 0; --bit) {
            unsigned int test = PM | (1u << bit);
            int c2 = (int)__popcll(__ballot(lmax >= test));
            if (c2 >= TOPK) {
                PM = test;
                if (c2 == TOPK) break;
            }
        }

        int cbase = 0;
#pragma unroll
        for (int j = 0; j < 32; ++j) {
            bool alive = (u[j] >= PM);
            unsigned long long m = __ballot(alive);
            if (alive) {
                int pos = cbase + (int)__popcll(m & lanelt);
                if (pos < 128) {
                    sclds[r][1024 + pos] = __uint_as_float(u[j]);
                    sclds[r][1280 + pos] = __uint_as_float((unsigned int)(j * 64 + lane));
                }
            }
            cbase += (int)__popcll(m);
        }
        const int Ncand = cbase;

        float dsum = 0.f;
        int   base = 0;

        if (Ncand <= 128) {
            const bool v0 = lane < Ncand;
            const bool v1 = 64 + lane < Ncand;
            const unsigned int c0 = v0 ? __float_as_uint(sclds[r][1024 + lane])      : 0u;
            const unsigned int c1 = v1 ? __float_as_uint(sclds[r][1024 + 64 + lane]) : 0u;
            const unsigned int i0 = v0 ? __float_as_uint(sclds[r][1280 + lane])      : 0u;
            const unsigned int i1 = v1 ? __float_as_uint(sclds[r][1280 + 64 + lane]) : 0u;

            unsigned int P = 0;
            for (int bit = 31; bit >= 0; --bit) {
                unsigned int test = P | (1u << bit);
                int c2 = (int)__popcll(__ballot(v0 && c0 >= test))
                       + (int)__popcll(__ballot(v1 && c1 >= test));
                if (c2 >= TOPK) {
                    P = test;
                    if (c2 == TOPK) break;
                }
            }

            {
                bool sel = v0 && (c0 >= P);
                unsigned long long m = __ballot(sel);
                if (sel) {
                    float e = __expf(inv_sortable(c0) - mx);
                    int pos = (int)__popcll(m & lanelt);
                    if (pos < SELCAP) {
                        sclds[r][pos]       = e;
                        sclds[r][512 + pos] = __uint_as_float(i0);
                    }
                    dsum += e;
                }
                base = (int)__popcll(m);
            }
            {
                bool sel = v1 && (c1 >= P);
                unsigned long long m = __ballot(sel);
                if (sel) {
                    float e = __expf(inv_sortable(c1) - mx);
                    int pos = base + (int)__popcll(m & lanelt);
                    if (pos < SELCAP) {
                        sclds[r][pos]       = e;
                        sclds[r][512 + pos] = __uint_as_float(i1);
                    }
                    dsum += e;
                }
                base += (int)__popcll(m);
            }
        } else {
            unsigned int P = 0;
            for (int bit = 31; bit >= 0; --bit) {
                unsigned int test = P | (1u << bit);
                int c2 = 0;
#pragma unroll
                for (int j = 0; j < 32; ++j)
                    c2 += (int)__popcll(__ballot(u[j] >= test));
                if (c2 >= TOPK) {
                    P = test;
                    if (c2 == TOPK) break;
                }
            }
#pragma unroll
            for (int j = 0; j < 32; ++j) {
                bool sel = (u[j] >= P);
                unsigned long long m = __ballot(sel);
                if (sel) {
                    float e = __expf(inv_sortable(u[j]) - mx);
                    int pos = base + (int)__popcll(m & lanelt);
                    if (pos < SELCAP) {
                        sclds[r][pos]       = e;
                        sclds[r][512 + pos] = __uint_as_float((unsigned int)(j * 64 + lane));
                    }
                    dsum += e;
                }
                base += (int)__popcll(m);
            }
        }
#pragma unroll
        for (int off = 32; off >= 1; off >>= 1)
            dsum += __shfl_xor(dsum, off, 64);

        // ---- PV gather, 8-deep ILP ----
        const int cn = base < SELCAP ? base : SELCAP;
        const float inv = 1.0f / dsum;
        const float* vb = Vp + (size_t)b * S * DM + h * DH + lane;

        float a0 = 0.f, a1 = 0.f, a2 = 0.f, a3 = 0.f;
        float a4 = 0.f, a5 = 0.f, a6 = 0.f, a7 = 0.f;
        int tt = 0;
        for (; tt + 8 <= cn; tt += 8) {
            int   s0 = (int)__float_as_uint(sclds[r][512 + tt + 0]);
            int   s1 = (int)__float_as_uint(sclds[r][512 + tt + 1]);
            int   s2 = (int)__float_as_uint(sclds[r][512 + tt + 2]);
            int   s3 = (int)__float_as_uint(sclds[r][512 + tt + 3]);
            int   s4 = (int)__float_as_uint(sclds[r][512 + tt + 4]);
            int   s5 = (int)__float_as_uint(sclds[r][512 + tt + 5]);
            int   s6 = (int)__float_as_uint(sclds[r][512 + tt + 6]);
            int   s7 = (int)__float_as_uint(sclds[r][512 + tt + 7]);
            float w0 = sclds[r][tt + 0], w1 = sclds[r][tt + 1];
            float w2 = sclds[r][tt + 2], w3 = sclds[r][tt + 3];
            float w4 = sclds[r][tt + 4], w5 = sclds[r][tt + 5];
            float w6 = sclds[r][tt + 6], w7 = sclds[r][tt + 7];
            a0 = fmaf(w0, vb[(size_t)s0 * DM], a0);
            a1 = fmaf(w1, vb[(size_t)s1 * DM], a1);
            a2 = fmaf(w2, vb[(size_t)s2 * DM], a2);
            a3 = fmaf(w3, vb[(size_t)s3 * DM], a3);
            a4 = fmaf(w4, vb[(size_t)s4 * DM], a4);
            a5 = fmaf(w5, vb[(size_t)s5 * DM], a5);
            a6 = fmaf(w6, vb[(size_t)s6 * DM], a6);
            a7 = fmaf(w7, vb[(size_t)s7 * DM], a7);
        }
        for (; tt < cn; ++tt) {
            int s0 = (int)__float_as_uint(sclds[r][512 + tt]);
            a0 = fmaf(sclds[r][tt], vb[(size_t)s0 * DM], a0);
        }
        Oh[(size_t)(b * L + lbase + r) * DM + h * DH + lane] =
            (((a0 + a1) + (a2 + a3)) + ((a4 + a5) + (a6 + a7))) * inv;
    }
}

// ---------------------------------------------------------------------------
extern "C" void kernel_launch(void* const* d_in, const int* in_sizes, int n_in,
                              void* d_out, int out_size, void* d_ws, size_t ws_size,
                              hipStream_t stream)
{
    const float* q  = (const float*)d_in[0];
    const float* k  = (const float*)d_in[1];
    const float* v  = (const float*)d_in[2];
    const float* Wq = (const float*)d_in[3];
    const float* bq = (const float*)d_in[4];
    const float* Wk = (const float*)d_in[5];
    const float* bk = (const float*)d_in[6];
    const float* Wv = (const float*)d_in[7];
    const float* bv = (const float*)d_in[8];
    const float* Wo = (const float*)d_in[9];
    const float* bo = (const float*)d_in[10];
    // d_in[11] = pos_bias: per-head additive constant -> top-k/softmax invariant -> no-op.

    float* out = (float*)d_out;
    char*  ws  = (char*)d_ws;

    const size_t MB = 1024 * 1024;
    float*          Qp = (float*)(ws);                       //  0-8 MiB
    unsigned short* Kf = (unsigned short*)(ws + 8 * MB);     //  8-20 MiB (fragment-ordered)
    float*          Vp = (float*)(ws + 20 * MB);             // 20-36
    float*          Oh = (float*)(ws + 36 * MB);             // 36-52
    unsigned short* WvH = (unsigned short*)(ws + 36 * MB);   // overlaps Oh head (dead until attn)
    unsigned short* WvL = (unsigned short*)(ws + 38 * MB);
    unsigned short* WoH = (unsigned short*)(ws + 52 * MB);   // 52-54
    unsigned short* WoL = (unsigned short*)(ws + 54 * MB);   // 54-56

    const int M = B * L;  // 4096
    dim3 blk(256);

    transpose_split_dual<<<dim3(DM / 32, DM / 32, 2), blk, 0, stream>>>(
        Wv, WvH, WvL, Wo, WoH, WoL, DM, DM);

    gemm_mfma_split<<<dim3(DM / 128, M / 128), blk, 0, stream>>>(v, WvH, WvL, bv, Vp, M, DM, DM);

    qk_proj<<<dim3((H * R) / 128, M / 128, 2), blk, 0, stream>>>(
        q, Wq, bq, Qp, k, Wk, bk, Kf, M, H * R, DM);

    score_select_gather<<<dim3(4096), dim3(512), 0, stream>>>(Qp, Kf, Vp, Oh);

    gemm_mfma_split<<<dim3(DM / 128, M / 128), blk, 0, stream>>>(Oh, WoH, WoL, bo, out, M, DM, DM);
}

// Round 20
// 468.555 us; speedup vs baseline: 1.1541x; 1.1541x over previous
//
#include <hip/hip_runtime.h>
#include <hip/hip_bf16.h>
#include <cstdint>

// Problem constants (match setup_inputs)
constexpr int B  = 2;
constexpr int L  = 2048;
constexpr int S  = 2048;
constexpr int DM = 1024;
constexpr int H  = 16;
constexpr int R  = 32;     // rank
constexpr int DH = 64;     // head dim
constexpr int TOPK = 32;
constexpr int SELCAP = 36;
constexpr float SCALE = 0.17677669529663687f; // 1/sqrt(32)

// MEASURED (R4-R19): VGPR cap = LDS/launch-bounds-implied occupancy; LICM ->
// opaque-zero asm. R18: 8 rows/block, 2 blk/CU, attn 234us. R19: 16 rows but
// 512-thread blocks -> 8 waves/CU (occupancy halved) -> 283us REGRESSION.
// R20: 16 rows with 1024-THREAD blocks -> 16 waves/CU (R18 residency) AND
// halved per-row K L2 traffic + halved per-wave selection. Bit-identical.

using short8 = __attribute__((ext_vector_type(8))) short;
using f32x4  = __attribute__((ext_vector_type(4))) float;

__device__ __forceinline__ unsigned short bf16_rne(float x) {
    unsigned int u = __float_as_uint(x);
    unsigned int r = u + 0x7FFFu + ((u >> 16) & 1u);
    return (unsigned short)(r >> 16);
}
__device__ __forceinline__ float bf16_up(unsigned short h) {
    return __uint_as_float((unsigned int)h << 16);
}
__device__ __forceinline__ float inv_sortable(unsigned int uu) {
    unsigned int sg2 = (unsigned int)(((int)uu) >> 31);
    return __uint_as_float(uu ^ (0x80000000u | ~sg2));
}

// ---------------------------------------------------------------------------
// Merged Q/K projection. z=0: Q -> fp32 Qp (pre-scaled). z=1: K -> 3-term
// bf16 splits in MFMA-fragment order (R17-proven).
// ---------------------------------------------------------------------------
__global__ __launch_bounds__(256, 2)
void qk_proj(const float* __restrict__ Aq, const float* __restrict__ Wq_,
             const float* __restrict__ bq_, float* __restrict__ Qp,
             const float* __restrict__ Ak, const float* __restrict__ Wk_,
             const float* __restrict__ bk_, unsigned short* __restrict__ Kf,
             int M, int N, int K)
{
    const int z = blockIdx.z;
    const float* A    = z ? Ak  : Aq;
    const float* W    = z ? Wk_ : Wq_;
    const float* bias = z ? bk_ : bq_;

    __shared__ float As[16][136];
    __shared__ float Ws[16][132];

    const int t  = threadIdx.x;
    const int tx = t & 15;
    const int ty = t >> 4;
    const int m0 = blockIdx.y * 128;
    const int n0 = blockIdx.x * 128;

    float acc[8][8];
#pragma unroll
    for (int i = 0; i < 8; ++i)
#pragma unroll
        for (int j = 0; j < 8; ++j) acc[i][j] = 0.f;

    for (int kb = 0; kb < K; kb += 16) {
        __syncthreads();
#pragma unroll
        for (int it = 0; it < 2; ++it) {
            int f4  = t + it * 256;
            int row = f4 >> 2;
            int cg  = (f4 & 3) * 4;
            float4 av = *(const float4*)&A[(size_t)(m0 + row) * K + kb + cg];
            As[cg + 0][row] = av.x;
            As[cg + 1][row] = av.y;
            As[cg + 2][row] = av.z;
            As[cg + 3][row] = av.w;
        }
#pragma unroll
        for (int it = 0; it < 2; ++it) {
            int f4 = t + it * 256;
            int kk = f4 >> 5;
            int cb = (f4 & 31) * 4;
            *(float4*)&Ws[kk][cb] = *(const float4*)&W[(size_t)(kb + kk) * N + n0 + cb];
        }
        __syncthreads();
#pragma unroll
        for (int kk = 0; kk < 16; ++kk) {
            float4 a0 = *(const float4*)&As[kk][ty * 8];
            float4 a1 = *(const float4*)&As[kk][ty * 8 + 4];
            float4 w0 = *(const float4*)&Ws[kk][tx * 8];
            float4 w1 = *(const float4*)&Ws[kk][tx * 8 + 4];
            float a[8] = {a0.x, a0.y, a0.z, a0.w, a1.x, a1.y, a1.z, a1.w};
            float w[8] = {w0.x, w0.y, w0.z, w0.w, w1.x, w1.y, w1.z, w1.w};
#pragma unroll
            for (int i = 0; i < 8; ++i)
#pragma unroll
                for (int j = 0; j < 8; ++j)
                    acc[i][j] = fmaf(a[i], w[j], acc[i][j]);
        }
    }

    float4 b0 = *(const float4*)&bias[n0 + tx * 8];
    float4 b1 = *(const float4*)&bias[n0 + tx * 8 + 4];

    if (z == 0) {
#pragma unroll
        for (int i = 0; i < 8; ++i) {
            float4 o0 = make_float4((acc[i][0] + b0.x) * SCALE, (acc[i][1] + b0.y) * SCALE,
                                    (acc[i][2] + b0.z) * SCALE, (acc[i][3] + b0.w) * SCALE);
            float4 o1 = make_float4((acc[i][4] + b1.x) * SCALE, (acc[i][5] + b1.y) * SCALE,
                                    (acc[i][6] + b1.z) * SCALE, (acc[i][7] + b1.w) * SCALE);
            size_t off = (size_t)(m0 + ty * 8 + i) * N + n0 + tx * 8;
            *(float4*)&Qp[off]     = o0;
            *(float4*)&Qp[off + 4] = o1;
        }
    } else {
        float bb[8] = {b0.x, b0.y, b0.z, b0.w, b1.x, b1.y, b1.z, b1.w};
        const int h2 = (n0 + tx * 8) >> 5;
        const int l4 = ((n0 + tx * 8) & 31) >> 3;
#pragma unroll
        for (int i = 0; i < 8; ++i) {
            unsigned short hh[8], mm[8], ll[8];
#pragma unroll
            for (int j = 0; j < 8; ++j) {
                float x = acc[i][j] + bb[j];
                hh[j] = bf16_rne(x);
                float xr = x - bf16_up(hh[j]);
                mm[j] = bf16_rne(xr);
                ll[j] = bf16_rne(xr - bf16_up(mm[j]));
            }
            const int grow = m0 + ty * 8 + i;
            const int bat  = grow >> 11;
            const int key  = grow & 2047;
            const int T    = key >> 4;
            const int l15  = key & 15;
            const size_t base = (((size_t)(bat * H + h2) * 128 + T) * 1536)
                              + (size_t)(l4 * 16 + l15) * 8;
            ushort4 h0v = {hh[0], hh[1], hh[2], hh[3]}, h1v = {hh[4], hh[5], hh[6], hh[7]};
            ushort4 m0v = {mm[0], mm[1], mm[2], mm[3]}, m1v = {mm[4], mm[5], mm[6], mm[7]};
            ushort4 l0v = {ll[0], ll[1], ll[2], ll[3]}, l1v = {ll[4], ll[5], ll[6], ll[7]};
            *(ushort4*)&Kf[base]            = h0v;
            *(ushort4*)&Kf[base + 4]        = h1v;
            *(ushort4*)&Kf[base + 512]      = m0v;
            *(ushort4*)&Kf[base + 512 + 4]  = m1v;
            *(ushort4*)&Kf[base + 1024]     = l0v;
            *(ushort4*)&Kf[base + 1024 + 4] = l1v;
        }
    }
}

// ---------------------------------------------------------------------------
// Dual transpose + split (R12-proven).
// ---------------------------------------------------------------------------
__global__ __launch_bounds__(256)
void transpose_split_dual(const float* __restrict__ Wv_, unsigned short* __restrict__ VhT,
                          unsigned short* __restrict__ VlT,
                          const float* __restrict__ Wo_, unsigned short* __restrict__ OhT,
                          unsigned short* __restrict__ OlT, int N, int K)
{
    const int z = blockIdx.z;
    const float* W = z ? Wo_ : Wv_;
    unsigned short* Th = z ? OhT : VhT;
    unsigned short* Tl = z ? OlT : VlT;

    __shared__ float tile[32][33];
    const int n0 = blockIdx.x * 32;
    const int k0 = blockIdx.y * 32;
    const int tx = threadIdx.x & 31;
    const int ty = threadIdx.x >> 5;

#pragma unroll
    for (int i = ty; i < 32; i += 8)
        tile[i][tx] = W[(size_t)(k0 + i) * N + n0 + tx];
    __syncthreads();
#pragma unroll
    for (int i = ty; i < 32; i += 8) {
        float x = tile[tx][i];
        unsigned short h = bf16_rne(x);
        float hf = bf16_up(h);
        unsigned short l = bf16_rne(x - hf);
        Th[(size_t)(n0 + i) * K + k0 + tx] = h;
        Tl[(size_t)(n0 + i) * K + k0 + tx] = l;
    }
}

// ---------------------------------------------------------------------------
// Split-bf16 MFMA GEMM (R11-proven).
// ---------------------------------------------------------------------------
__global__ __launch_bounds__(256, 1)
void gemm_mfma_split(const float* __restrict__ A, const unsigned short* __restrict__ Bh,
                     const unsigned short* __restrict__ Bl, const float* __restrict__ bias,
                     float* __restrict__ C, int M, int N, int K)
{
    constexpr int LDT = 56;
    __shared__ unsigned short Ah[128 * LDT];
    __shared__ unsigned short Al[128 * LDT];
    __shared__ unsigned short Wh[128 * LDT];
    __shared__ unsigned short Wl[128 * LDT];

    const int t    = threadIdx.x;
    const int lane = t & 63;
    const int w    = t >> 6;
    const int wr   = w >> 1;
    const int wc   = w & 1;
    const int l15  = lane & 15;
    const int l4   = lane >> 4;
    const int m0   = blockIdx.y * 128;
    const int n0   = blockIdx.x * 128;

    f32x4 acc[4][4];
#pragma unroll
    for (int m = 0; m < 4; ++m)
#pragma unroll
        for (int n = 0; n < 4; ++n) {
            f32x4 z = {0.f, 0.f, 0.f, 0.f};
            acc[m][n] = z;
        }

#pragma unroll 1
    for (int kb = 0; kb < K; kb += 32) {
        __syncthreads();
#pragma unroll
        for (int it = 0; it < 4; ++it) {
            int f   = t + it * 256;
            int row = f >> 3;
            int kg  = (f & 7) * 4;
            float4 av = *(const float4*)&A[(size_t)(m0 + row) * K + kb + kg];
            ushort4 hv, lv;
            hv.x = bf16_rne(av.x); lv.x = bf16_rne(av.x - bf16_up(hv.x));
            hv.y = bf16_rne(av.y); lv.y = bf16_rne(av.y - bf16_up(hv.y));
            hv.z = bf16_rne(av.z); lv.z = bf16_rne(av.z - bf16_up(hv.z));
            hv.w = bf16_rne(av.w); lv.w = bf16_rne(av.w - bf16_up(hv.w));
            *(ushort4*)&Ah[row * LDT + kg] = hv;
            *(ushort4*)&Al[row * LDT + kg] = lv;
            ushort4 bh4 = *(const ushort4*)&Bh[(size_t)(n0 + row) * K + kb + kg];
            ushort4 bl4 = *(const ushort4*)&Bl[(size_t)(n0 + row) * K + kb + kg];
            *(ushort4*)&Wh[row * LDT + kg] = bh4;
            *(ushort4*)&Wl[row * LDT + kg] = bl4;
        }
        __syncthreads();

        short8 ah[4], al[4], bh[4], bl[4];
#pragma unroll
        for (int m = 0; m < 4; ++m) {
            int row = wr * 64 + m * 16 + l15;
            ah[m] = *(short8*)&Ah[row * LDT + l4 * 8];
            al[m] = *(short8*)&Al[row * LDT + l4 * 8];
        }
#pragma unroll
        for (int n = 0; n < 4; ++n) {
            int col = wc * 64 + n * 16 + l15;
            bh[n] = *(short8*)&Wh[col * LDT + l4 * 8];
            bl[n] = *(short8*)&Wl[col * LDT + l4 * 8];
        }
#pragma unroll
        for (int m = 0; m < 4; ++m)
#pragma unroll
            for (int n = 0; n < 4; ++n)
                acc[m][n] = __builtin_amdgcn_mfma_f32_16x16x32_bf16(ah[m], bh[n], acc[m][n], 0, 0, 0);
#pragma unroll
        for (int m = 0; m < 4; ++m)
#pragma unroll
            for (int n = 0; n < 4; ++n)
                acc[m][n] = __builtin_amdgcn_mfma_f32_16x16x32_bf16(ah[m], bl[n], acc[m][n], 0, 0, 0);
#pragma unroll
        for (int m = 0; m < 4; ++m)
#pragma unroll
            for (int n = 0; n < 4; ++n)
                acc[m][n] = __builtin_amdgcn_mfma_f32_16x16x32_bf16(al[m], bh[n], acc[m][n], 0, 0, 0);
    }

#pragma unroll
    for (int m = 0; m < 4; ++m) {
        int row = m0 + wr * 64 + m * 16 + l4 * 4;
#pragma unroll
        for (int n = 0; n < 4; ++n) {
            int col = n0 + wc * 64 + n * 16 + l15;
            float bv = bias[col];
#pragma unroll
            for (int r = 0; r < 4; ++r)
                C[(size_t)(row + r) * N + col] = acc[m][n][r] + bv;
        }
    }
}

// ---------------------------------------------------------------------------
// Fused MFMA score + candidate-pruned exact top-k + softmax + PV gather.
// v20: 16 real rows/block with 1024-THREAD blocks (16 waves) -> 16 waves/CU
// (R18 residency) at 1 blk/CU, while K L2 traffic per row and per-wave
// selection work both halve vs R18. Per-(row,key) arithmetic identical ->
// bit-identical output. Wave wv: score keys [wv*128, wv*128+128), then
// selection+gather for row wv.
// ---------------------------------------------------------------------------
__global__ __launch_bounds__(1024, 1)
void score_select_gather(const float* __restrict__ Qp,
                         const unsigned short* __restrict__ Kf,
                         const float* __restrict__ Vp, float* __restrict__ Oh)
{
    constexpr int LDS_STRIDE = 2049;
    __shared__ float sclds[16][LDS_STRIDE];    // 131136 B
    __shared__ unsigned short Qs[3][16][32];   // 3 KB

    const int t    = threadIdx.x;
    const int lane = t & 63;
    const int wv   = t >> 6;            // 0..15

    const int wgid = blockIdx.x;             // 0..4095
    const int xcd  = wgid & 7;
    const int jj   = wgid >> 3;              // 0..511
    const int bh_  = xcd + 8 * (jj >> 7);    // 0..31
    const int tile = jj & 127;
    const int b    = bh_ >> 4;
    const int h    = bh_ & 15;
    const int lbase = tile * 16;

    // stage + split Q: 16 rows x 32 (all real)
    if (t < 512) {
        int row = t >> 5;       // 0..15
        int col = t & 31;
        float x = Qp[(size_t)(b * L + lbase + row) * (H * R) + h * R + col];
        unsigned short hh = bf16_rne(x);
        float xr = x - bf16_up(hh);
        unsigned short mm = bf16_rne(xr);
        unsigned short ll = bf16_rne(xr - bf16_up(mm));
        Qs[0][row][col] = hh;
        Qs[1][row][col] = mm;
        Qs[2][row][col] = ll;
    }
    __syncthreads();

    const int l15 = lane & 15;
    const int l4  = lane >> 4;

    const short8 ah = *(const short8*)&Qs[0][l15][l4 * 8];
    const short8 am = *(const short8*)&Qs[1][l15][l4 * 8];
    const short8 al = *(const short8*)&Qs[2][l15][l4 * 8];

    const unsigned short* kfb = Kf + (size_t)bh_ * 128 * 1536;

    // wave wv owns keys [wv*128, wv*128+128) = 8 T-tiles, 4 iters x 2 tiles
#pragma unroll 1
    for (int p = 0; p < 4; ++p) {
        const int T0 = wv * 8 + p * 2;
        const unsigned short* t0 = kfb + (size_t)T0 * 1536 + lane * 8;
        const unsigned short* t1 = t0 + 1536;
        const short8 bh0 = *(const short8*)(t0);
        const short8 bm0 = *(const short8*)(t0 + 512);
        const short8 bl0 = *(const short8*)(t0 + 1024);
        const short8 bh1 = *(const short8*)(t1);
        const short8 bm1 = *(const short8*)(t1 + 512);
        const short8 bl1 = *(const short8*)(t1 + 1024);

        f32x4 acc0 = {0.f, 0.f, 0.f, 0.f};
        f32x4 acc1 = {0.f, 0.f, 0.f, 0.f};
        acc0 = __builtin_amdgcn_mfma_f32_16x16x32_bf16(ah, bh0, acc0, 0, 0, 0);
        acc1 = __builtin_amdgcn_mfma_f32_16x16x32_bf16(ah, bh1, acc1, 0, 0, 0);
        acc0 = __builtin_amdgcn_mfma_f32_16x16x32_bf16(ah, bm0, acc0, 0, 0, 0);
        acc1 = __builtin_amdgcn_mfma_f32_16x16x32_bf16(ah, bm1, acc1, 0, 0, 0);
        acc0 = __builtin_amdgcn_mfma_f32_16x16x32_bf16(am, bh0, acc0, 0, 0, 0);
        acc1 = __builtin_amdgcn_mfma_f32_16x16x32_bf16(am, bh1, acc1, 0, 0, 0);
        acc0 = __builtin_amdgcn_mfma_f32_16x16x32_bf16(am, bm0, acc0, 0, 0, 0);
        acc1 = __builtin_amdgcn_mfma_f32_16x16x32_bf16(am, bm1, acc1, 0, 0, 0);
        acc0 = __builtin_amdgcn_mfma_f32_16x16x32_bf16(ah, bl0, acc0, 0, 0, 0);
        acc1 = __builtin_amdgcn_mfma_f32_16x16x32_bf16(ah, bl1, acc1, 0, 0, 0);
        acc0 = __builtin_amdgcn_mfma_f32_16x16x32_bf16(al, bh0, acc0, 0, 0, 0);
        acc1 = __builtin_amdgcn_mfma_f32_16x16x32_bf16(al, bh1, acc1, 0, 0, 0);

        const int kc0 = wv * 128 + p * 32 + l15;
#pragma unroll
        for (int r = 0; r < 4; ++r) {
            sclds[l4 * 4 + r][kc0]      = acc0[r];
            sclds[l4 * 4 + r][kc0 + 16] = acc1[r];
        }
    }

    __syncthreads();

    const unsigned long long lanelt = (1ull << lane) - 1ull;
    {
        const int r = wv;   // one row per wave

        unsigned int u[32];
#pragma unroll
        for (int j = 0; j < 32; ++j) {
            unsigned int bb  = __float_as_uint(sclds[r][j * 64 + lane]);
            unsigned int sgn = (unsigned int)(((int)bb) >> 31);
            u[j] = bb ^ (sgn | 0x80000000u);
        }

        unsigned int lmax = u[0];
#pragma unroll
        for (int j = 1; j < 32; ++j) lmax = lmax > u[j] ? lmax : u[j];
        unsigned int umx = lmax;
#pragma unroll
        for (int off = 32; off >= 1; off >>= 1) {
            unsigned int o = (unsigned int)__shfl_xor((int)umx, off, 64);
            umx = umx > o ? umx : o;
        }
        const float mx = inv_sortable(umx);

        unsigned int PM = 0;
        for (int bit = 31; bit >= 0; --bit) {
            unsigned int test = PM | (1u << bit);
            int c2 = (int)__popcll(__ballot(lmax >= test));
            if (c2 >= TOPK) {
                PM = test;
                if (c2 == TOPK) break;
            }
        }

        int cbase = 0;
#pragma unroll
        for (int j = 0; j < 32; ++j) {
            bool alive = (u[j] >= PM);
            unsigned long long m = __ballot(alive);
            if (alive) {
                int pos = cbase + (int)__popcll(m & lanelt);
                if (pos < 128) {
                    sclds[r][1024 + pos] = __uint_as_float(u[j]);
                    sclds[r][1280 + pos] = __uint_as_float((unsigned int)(j * 64 + lane));
                }
            }
            cbase += (int)__popcll(m);
        }
        const int Ncand = cbase;

        float dsum = 0.f;
        int   base = 0;

        if (Ncand <= 128) {
            const bool v0 = lane < Ncand;
            const bool v1 = 64 + lane < Ncand;
            const unsigned int c0 = v0 ? __float_as_uint(sclds[r][1024 + lane])      : 0u;
            const unsigned int c1 = v1 ? __float_as_uint(sclds[r][1024 + 64 + lane]) : 0u;
            const unsigned int i0 = v0 ? __float_as_uint(sclds[r][1280 + lane])      : 0u;
            const unsigned int i1 = v1 ? __float_as_uint(sclds[r][1280 + 64 + lane]) : 0u;

            unsigned int P = 0;
            for (int bit = 31; bit >= 0; --bit) {
                unsigned int test = P | (1u << bit);
                int c2 = (int)__popcll(__ballot(v0 && c0 >= test))
                       + (int)__popcll(__ballot(v1 && c1 >= test));
                if (c2 >= TOPK) {
                    P = test;
                    if (c2 == TOPK) break;
                }
            }

            {
                bool sel = v0 && (c0 >= P);
                unsigned long long m = __ballot(sel);
                if (sel) {
                    float e = __expf(inv_sortable(c0) - mx);
                    int pos = (int)__popcll(m & lanelt);
                    if (pos < SELCAP) {
                        sclds[r][pos]       = e;
                        sclds[r][512 + pos] = __uint_as_float(i0);
                    }
                    dsum += e;
                }
                base = (int)__popcll(m);
            }
            {
                bool sel = v1 && (c1 >= P);
                unsigned long long m = __ballot(sel);
                if (sel) {
                    float e = __expf(inv_sortable(c1) - mx);
                    int pos = base + (int)__popcll(m & lanelt);
                    if (pos < SELCAP) {
                        sclds[r][pos]       = e;
                        sclds[r][512 + pos] = __uint_as_float(i1);
                    }
                    dsum += e;
                }
                base += (int)__popcll(m);
            }
        } else {
            unsigned int P = 0;
            for (int bit = 31; bit >= 0; --bit) {
                unsigned int test = P | (1u << bit);
                int c2 = 0;
#pragma unroll
                for (int j = 0; j < 32; ++j)
                    c2 += (int)__popcll(__ballot(u[j] >= test));
                if (c2 >= TOPK) {
                    P = test;
                    if (c2 == TOPK) break;
                }
            }
#pragma unroll
            for (int j = 0; j < 32; ++j) {
                bool sel = (u[j] >= P);
                unsigned long long m = __ballot(sel);
                if (sel) {
                    float e = __expf(inv_sortable(u[j]) - mx);
                    int pos = base + (int)__popcll(m & lanelt);
                    if (pos < SELCAP) {
                        sclds[r][pos]       = e;
                        sclds[r][512 + pos] = __uint_as_float((unsigned int)(j * 64 + lane));
                    }
                    dsum += e;
                }
                base += (int)__popcll(m);
            }
        }
#pragma unroll
        for (int off = 32; off >= 1; off >>= 1)
            dsum += __shfl_xor(dsum, off, 64);

        // ---- PV gather, 8-deep ILP ----
        const int cn = base < SELCAP ? base : SELCAP;
        const float inv = 1.0f / dsum;
        const float* vb = Vp + (size_t)b * S * DM + h * DH + lane;

        float a0 = 0.f, a1 = 0.f, a2 = 0.f, a3 = 0.f;
        float a4 = 0.f, a5 = 0.f, a6 = 0.f, a7 = 0.f;
        int tt = 0;
        for (; tt + 8 <= cn; tt += 8) {
            int   s0 = (int)__float_as_uint(sclds[r][512 + tt + 0]);
            int   s1 = (int)__float_as_uint(sclds[r][512 + tt + 1]);
            int   s2 = (int)__float_as_uint(sclds[r][512 + tt + 2]);
            int   s3 = (int)__float_as_uint(sclds[r][512 + tt + 3]);
            int   s4 = (int)__float_as_uint(sclds[r][512 + tt + 4]);
            int   s5 = (int)__float_as_uint(sclds[r][512 + tt + 5]);
            int   s6 = (int)__float_as_uint(sclds[r][512 + tt + 6]);
            int   s7 = (int)__float_as_uint(sclds[r][512 + tt + 7]);
            float w0 = sclds[r][tt + 0], w1 = sclds[r][tt + 1];
            float w2 = sclds[r][tt + 2], w3 = sclds[r][tt + 3];
            float w4 = sclds[r][tt + 4], w5 = sclds[r][tt + 5];
            float w6 = sclds[r][tt + 6], w7 = sclds[r][tt + 7];
            a0 = fmaf(w0, vb[(size_t)s0 * DM], a0);
            a1 = fmaf(w1, vb[(size_t)s1 * DM], a1);
            a2 = fmaf(w2, vb[(size_t)s2 * DM], a2);
            a3 = fmaf(w3, vb[(size_t)s3 * DM], a3);
            a4 = fmaf(w4, vb[(size_t)s4 * DM], a4);
            a5 = fmaf(w5, vb[(size_t)s5 * DM], a5);
            a6 = fmaf(w6, vb[(size_t)s6 * DM], a6);
            a7 = fmaf(w7, vb[(size_t)s7 * DM], a7);
        }
        for (; tt < cn; ++tt) {
            int s0 = (int)__float_as_uint(sclds[r][512 + tt]);
            a0 = fmaf(sclds[r][tt], vb[(size_t)s0 * DM], a0);
        }
        Oh[(size_t)(b * L + lbase + r) * DM + h * DH + lane] =
            (((a0 + a1) + (a2 + a3)) + ((a4 + a5) + (a6 + a7))) * inv;
    }
}

// ---------------------------------------------------------------------------
extern "C" void kernel_launch(void* const* d_in, const int* in_sizes, int n_in,
                              void* d_out, int out_size, void* d_ws, size_t ws_size,
                              hipStream_t stream)
{
    const float* q  = (const float*)d_in[0];
    const float* k  = (const float*)d_in[1];
    const float* v  = (const float*)d_in[2];
    const float* Wq = (const float*)d_in[3];
    const float* bq = (const float*)d_in[4];
    const float* Wk = (const float*)d_in[5];
    const float* bk = (const float*)d_in[6];
    const float* Wv = (const float*)d_in[7];
    const float* bv = (const float*)d_in[8];
    const float* Wo = (const float*)d_in[9];
    const float* bo = (const float*)d_in[10];
    // d_in[11] = pos_bias: per-head additive constant -> top-k/softmax invariant -> no-op.

    float* out = (float*)d_out;
    char*  ws  = (char*)d_ws;

    const size_t MB = 1024 * 1024;
    float*          Qp = (float*)(ws);                       //  0-8 MiB
    unsigned short* Kf = (unsigned short*)(ws + 8 * MB);     //  8-20 MiB (fragment-ordered)
    float*          Vp = (float*)(ws + 20 * MB);             // 20-36
    float*          Oh = (float*)(ws + 36 * MB);             // 36-52
    unsigned short* WvH = (unsigned short*)(ws + 36 * MB);   // overlaps Oh head (dead until attn)
    unsigned short* WvL = (unsigned short*)(ws + 38 * MB);
    unsigned short* WoH = (unsigned short*)(ws + 52 * MB);   // 52-54
    unsigned short* WoL = (unsigned short*)(ws + 54 * MB);   // 54-56

    const int M = B * L;  // 4096
    dim3 blk(256);

    transpose_split_dual<<<dim3(DM / 32, DM / 32, 2), blk, 0, stream>>>(
        Wv, WvH, WvL, Wo, WoH, WoL, DM, DM);

    gemm_mfma_split<<<dim3(DM / 128, M / 128), blk, 0, stream>>>(v, WvH, WvL, bv, Vp, M, DM, DM);

    qk_proj<<<dim3((H * R) / 128, M / 128, 2), blk, 0, stream>>>(
        q, Wq, bq, Qp, k, Wk, bk, Kf, M, H * R, DM);

    score_select_gather<<<dim3(4096), dim3(1024), 0, stream>>>(Qp, Kf, Vp, Oh);

    gemm_mfma_split<<<dim3(DM / 128, M / 128), blk, 0, stream>>>(Oh, WoH, WoL, bo, out, M, DM, DM);
}

// Round 21
// 465.754 us; speedup vs baseline: 1.1610x; 1.0060x over previous
//
#include <hip/hip_runtime.h>
#include <hip/hip_bf16.h>
#include <cstdint>

// Problem constants (match setup_inputs)
constexpr int B  = 2;
constexpr int L  = 2048;
constexpr int S  = 2048;
constexpr int DM = 1024;
constexpr int H  = 16;
constexpr int R  = 32;     // rank
constexpr int DH = 64;     // head dim
constexpr int TOPK = 32;
constexpr int SELCAP = 36;
constexpr float SCALE = 0.17677669529663687f; // 1/sqrt(32)

// MEASURED (R4-R20): VGPR cap = LDS/launch-bounds-implied occupancy; LICM ->
// opaque-zero asm. R20: 16 rows x 1024-thread blocks, attn 210us (total 468).
// R21: double-buffered K-fragment loads (R4-proven explicit 2-buffer shape)
// hide L2 latency under MFMA; setprio(1) around MFMA clusters (T5).
// Arithmetic order unchanged -> bit-identical output.

using short8 = __attribute__((ext_vector_type(8))) short;
using f32x4  = __attribute__((ext_vector_type(4))) float;

__device__ __forceinline__ unsigned short bf16_rne(float x) {
    unsigned int u = __float_as_uint(x);
    unsigned int r = u + 0x7FFFu + ((u >> 16) & 1u);
    return (unsigned short)(r >> 16);
}
__device__ __forceinline__ float bf16_up(unsigned short h) {
    return __uint_as_float((unsigned int)h << 16);
}
__device__ __forceinline__ float inv_sortable(unsigned int uu) {
    unsigned int sg2 = (unsigned int)(((int)uu) >> 31);
    return __uint_as_float(uu ^ (0x80000000u | ~sg2));
}

// ---------------------------------------------------------------------------
// Merged Q/K projection. z=0: Q -> fp32 Qp (pre-scaled). z=1: K -> 3-term
// bf16 splits in MFMA-fragment order (R17-proven).
// ---------------------------------------------------------------------------
__global__ __launch_bounds__(256, 2)
void qk_proj(const float* __restrict__ Aq, const float* __restrict__ Wq_,
             const float* __restrict__ bq_, float* __restrict__ Qp,
             const float* __restrict__ Ak, const float* __restrict__ Wk_,
             const float* __restrict__ bk_, unsigned short* __restrict__ Kf,
             int M, int N, int K)
{
    const int z = blockIdx.z;
    const float* A    = z ? Ak  : Aq;
    const float* W    = z ? Wk_ : Wq_;
    const float* bias = z ? bk_ : bq_;

    __shared__ float As[16][136];
    __shared__ float Ws[16][132];

    const int t  = threadIdx.x;
    const int tx = t & 15;
    const int ty = t >> 4;
    const int m0 = blockIdx.y * 128;
    const int n0 = blockIdx.x * 128;

    float acc[8][8];
#pragma unroll
    for (int i = 0; i < 8; ++i)
#pragma unroll
        for (int j = 0; j < 8; ++j) acc[i][j] = 0.f;

    for (int kb = 0; kb < K; kb += 16) {
        __syncthreads();
#pragma unroll
        for (int it = 0; it < 2; ++it) {
            int f4  = t + it * 256;
            int row = f4 >> 2;
            int cg  = (f4 & 3) * 4;
            float4 av = *(const float4*)&A[(size_t)(m0 + row) * K + kb + cg];
            As[cg + 0][row] = av.x;
            As[cg + 1][row] = av.y;
            As[cg + 2][row] = av.z;
            As[cg + 3][row] = av.w;
        }
#pragma unroll
        for (int it = 0; it < 2; ++it) {
            int f4 = t + it * 256;
            int kk = f4 >> 5;
            int cb = (f4 & 31) * 4;
            *(float4*)&Ws[kk][cb] = *(const float4*)&W[(size_t)(kb + kk) * N + n0 + cb];
        }
        __syncthreads();
#pragma unroll
        for (int kk = 0; kk < 16; ++kk) {
            float4 a0 = *(const float4*)&As[kk][ty * 8];
            float4 a1 = *(const float4*)&As[kk][ty * 8 + 4];
            float4 w0 = *(const float4*)&Ws[kk][tx * 8];
            float4 w1 = *(const float4*)&Ws[kk][tx * 8 + 4];
            float a[8] = {a0.x, a0.y, a0.z, a0.w, a1.x, a1.y, a1.z, a1.w};
            float w[8] = {w0.x, w0.y, w0.z, w0.w, w1.x, w1.y, w1.z, w1.w};
#pragma unroll
            for (int i = 0; i < 8; ++i)
#pragma unroll
                for (int j = 0; j < 8; ++j)
                    acc[i][j] = fmaf(a[i], w[j], acc[i][j]);
        }
    }

    float4 b0 = *(const float4*)&bias[n0 + tx * 8];
    float4 b1 = *(const float4*)&bias[n0 + tx * 8 + 4];

    if (z == 0) {
#pragma unroll
        for (int i = 0; i < 8; ++i) {
            float4 o0 = make_float4((acc[i][0] + b0.x) * SCALE, (acc[i][1] + b0.y) * SCALE,
                                    (acc[i][2] + b0.z) * SCALE, (acc[i][3] + b0.w) * SCALE);
            float4 o1 = make_float4((acc[i][4] + b1.x) * SCALE, (acc[i][5] + b1.y) * SCALE,
                                    (acc[i][6] + b1.z) * SCALE, (acc[i][7] + b1.w) * SCALE);
            size_t off = (size_t)(m0 + ty * 8 + i) * N + n0 + tx * 8;
            *(float4*)&Qp[off]     = o0;
            *(float4*)&Qp[off + 4] = o1;
        }
    } else {
        float bb[8] = {b0.x, b0.y, b0.z, b0.w, b1.x, b1.y, b1.z, b1.w};
        const int h2 = (n0 + tx * 8) >> 5;
        const int l4 = ((n0 + tx * 8) & 31) >> 3;
#pragma unroll
        for (int i = 0; i < 8; ++i) {
            unsigned short hh[8], mm[8], ll[8];
#pragma unroll
            for (int j = 0; j < 8; ++j) {
                float x = acc[i][j] + bb[j];
                hh[j] = bf16_rne(x);
                float xr = x - bf16_up(hh[j]);
                mm[j] = bf16_rne(xr);
                ll[j] = bf16_rne(xr - bf16_up(mm[j]));
            }
            const int grow = m0 + ty * 8 + i;
            const int bat  = grow >> 11;
            const int key  = grow & 2047;
            const int T    = key >> 4;
            const int l15  = key & 15;
            const size_t base = (((size_t)(bat * H + h2) * 128 + T) * 1536)
                              + (size_t)(l4 * 16 + l15) * 8;
            ushort4 h0v = {hh[0], hh[1], hh[2], hh[3]}, h1v = {hh[4], hh[5], hh[6], hh[7]};
            ushort4 m0v = {mm[0], mm[1], mm[2], mm[3]}, m1v = {mm[4], mm[5], mm[6], mm[7]};
            ushort4 l0v = {ll[0], ll[1], ll[2], ll[3]}, l1v = {ll[4], ll[5], ll[6], ll[7]};
            *(ushort4*)&Kf[base]            = h0v;
            *(ushort4*)&Kf[base + 4]        = h1v;
            *(ushort4*)&Kf[base + 512]      = m0v;
            *(ushort4*)&Kf[base + 512 + 4]  = m1v;
            *(ushort4*)&Kf[base + 1024]     = l0v;
            *(ushort4*)&Kf[base + 1024 + 4] = l1v;
        }
    }
}

// ---------------------------------------------------------------------------
// Dual transpose + split (R12-proven).
// ---------------------------------------------------------------------------
__global__ __launch_bounds__(256)
void transpose_split_dual(const float* __restrict__ Wv_, unsigned short* __restrict__ VhT,
                          unsigned short* __restrict__ VlT,
                          const float* __restrict__ Wo_, unsigned short* __restrict__ OhT,
                          unsigned short* __restrict__ OlT, int N, int K)
{
    const int z = blockIdx.z;
    const float* W = z ? Wo_ : Wv_;
    unsigned short* Th = z ? OhT : VhT;
    unsigned short* Tl = z ? OlT : VlT;

    __shared__ float tile[32][33];
    const int n0 = blockIdx.x * 32;
    const int k0 = blockIdx.y * 32;
    const int tx = threadIdx.x & 31;
    const int ty = threadIdx.x >> 5;

#pragma unroll
    for (int i = ty; i < 32; i += 8)
        tile[i][tx] = W[(size_t)(k0 + i) * N + n0 + tx];
    __syncthreads();
#pragma unroll
    for (int i = ty; i < 32; i += 8) {
        float x = tile[tx][i];
        unsigned short h = bf16_rne(x);
        float hf = bf16_up(h);
        unsigned short l = bf16_rne(x - hf);
        Th[(size_t)(n0 + i) * K + k0 + tx] = h;
        Tl[(size_t)(n0 + i) * K + k0 + tx] = l;
    }
}

// ---------------------------------------------------------------------------
// Split-bf16 MFMA GEMM (R11-proven).
// ---------------------------------------------------------------------------
__global__ __launch_bounds__(256, 1)
void gemm_mfma_split(const float* __restrict__ A, const unsigned short* __restrict__ Bh,
                     const unsigned short* __restrict__ Bl, const float* __restrict__ bias,
                     float* __restrict__ C, int M, int N, int K)
{
    constexpr int LDT = 56;
    __shared__ unsigned short Ah[128 * LDT];
    __shared__ unsigned short Al[128 * LDT];
    __shared__ unsigned short Wh[128 * LDT];
    __shared__ unsigned short Wl[128 * LDT];

    const int t    = threadIdx.x;
    const int lane = t & 63;
    const int w    = t >> 6;
    const int wr   = w >> 1;
    const int wc   = w & 1;
    const int l15  = lane & 15;
    const int l4   = lane >> 4;
    const int m0   = blockIdx.y * 128;
    const int n0   = blockIdx.x * 128;

    f32x4 acc[4][4];
#pragma unroll
    for (int m = 0; m < 4; ++m)
#pragma unroll
        for (int n = 0; n < 4; ++n) {
            f32x4 z = {0.f, 0.f, 0.f, 0.f};
            acc[m][n] = z;
        }

#pragma unroll 1
    for (int kb = 0; kb < K; kb += 32) {
        __syncthreads();
#pragma unroll
        for (int it = 0; it < 4; ++it) {
            int f   = t + it * 256;
            int row = f >> 3;
            int kg  = (f & 7) * 4;
            float4 av = *(const float4*)&A[(size_t)(m0 + row) * K + kb + kg];
            ushort4 hv, lv;
            hv.x = bf16_rne(av.x); lv.x = bf16_rne(av.x - bf16_up(hv.x));
            hv.y = bf16_rne(av.y); lv.y = bf16_rne(av.y - bf16_up(hv.y));
            hv.z = bf16_rne(av.z); lv.z = bf16_rne(av.z - bf16_up(hv.z));
            hv.w = bf16_rne(av.w); lv.w = bf16_rne(av.w - bf16_up(hv.w));
            *(ushort4*)&Ah[row * LDT + kg] = hv;
            *(ushort4*)&Al[row * LDT + kg] = lv;
            ushort4 bh4 = *(const ushort4*)&Bh[(size_t)(n0 + row) * K + kb + kg];
            ushort4 bl4 = *(const ushort4*)&Bl[(size_t)(n0 + row) * K + kb + kg];
            *(ushort4*)&Wh[row * LDT + kg] = bh4;
            *(ushort4*)&Wl[row * LDT + kg] = bl4;
        }
        __syncthreads();

        short8 ah[4], al[4], bh[4], bl[4];
#pragma unroll
        for (int m = 0; m < 4; ++m) {
            int row = wr * 64 + m * 16 + l15;
            ah[m] = *(short8*)&Ah[row * LDT + l4 * 8];
            al[m] = *(short8*)&Al[row * LDT + l4 * 8];
        }
#pragma unroll
        for (int n = 0; n < 4; ++n) {
            int col = wc * 64 + n * 16 + l15;
            bh[n] = *(short8*)&Wh[col * LDT + l4 * 8];
            bl[n] = *(short8*)&Wl[col * LDT + l4 * 8];
        }
#pragma unroll
        for (int m = 0; m < 4; ++m)
#pragma unroll
            for (int n = 0; n < 4; ++n)
                acc[m][n] = __builtin_amdgcn_mfma_f32_16x16x32_bf16(ah[m], bh[n], acc[m][n], 0, 0, 0);
#pragma unroll
        for (int m = 0; m < 4; ++m)
#pragma unroll
            for (int n = 0; n < 4; ++n)
                acc[m][n] = __builtin_amdgcn_mfma_f32_16x16x32_bf16(ah[m], bl[n], acc[m][n], 0, 0, 0);
#pragma unroll
        for (int m = 0; m < 4; ++m)
#pragma unroll
            for (int n = 0; n < 4; ++n)
                acc[m][n] = __builtin_amdgcn_mfma_f32_16x16x32_bf16(al[m], bh[n], acc[m][n], 0, 0, 0);
    }

#pragma unroll
    for (int m = 0; m < 4; ++m) {
        int row = m0 + wr * 64 + m * 16 + l4 * 4;
#pragma unroll
        for (int n = 0; n < 4; ++n) {
            int col = n0 + wc * 64 + n * 16 + l15;
            float bv = bias[col];
#pragma unroll
            for (int r = 0; r < 4; ++r)
                C[(size_t)(row + r) * N + col] = acc[m][n][r] + bv;
        }
    }
}

// ---------------------------------------------------------------------------
// Fused MFMA score + candidate-pruned exact top-k + softmax + PV gather.
// v21 = v20 + double-buffered K-fragment loads (loads for tile-pair p+1
// issued before tile-pair p's MFMAs -> L2 latency hidden under compute) +
// s_setprio(1) around MFMA clusters. Arithmetic order identical to v20 ->
// bit-identical output.
// ---------------------------------------------------------------------------
__global__ __launch_bounds__(1024, 1)
void score_select_gather(const float* __restrict__ Qp,
                         const unsigned short* __restrict__ Kf,
                         const float* __restrict__ Vp, float* __restrict__ Oh)
{
    constexpr int LDS_STRIDE = 2049;
    __shared__ float sclds[16][LDS_STRIDE];    // 131136 B
    __shared__ unsigned short Qs[3][16][32];   // 3 KB

    const int t    = threadIdx.x;
    const int lane = t & 63;
    const int wv   = t >> 6;            // 0..15

    const int wgid = blockIdx.x;             // 0..4095
    const int xcd  = wgid & 7;
    const int jj   = wgid >> 3;              // 0..511
    const int bh_  = xcd + 8 * (jj >> 7);    // 0..31
    const int tile = jj & 127;
    const int b    = bh_ >> 4;
    const int h    = bh_ & 15;
    const int lbase = tile * 16;

    // stage + split Q: 16 rows x 32 (all real)
    if (t < 512) {
        int row = t >> 5;       // 0..15
        int col = t & 31;
        float x = Qp[(size_t)(b * L + lbase + row) * (H * R) + h * R + col];
        unsigned short hh = bf16_rne(x);
        float xr = x - bf16_up(hh);
        unsigned short mm = bf16_rne(xr);
        unsigned short ll = bf16_rne(xr - bf16_up(mm));
        Qs[0][row][col] = hh;
        Qs[1][row][col] = mm;
        Qs[2][row][col] = ll;
    }
    __syncthreads();

    const int l15 = lane & 15;
    const int l4  = lane >> 4;

    const short8 ah = *(const short8*)&Qs[0][l15][l4 * 8];
    const short8 am = *(const short8*)&Qs[1][l15][l4 * 8];
    const short8 al = *(const short8*)&Qs[2][l15][l4 * 8];

    const unsigned short* kfb = Kf + (size_t)bh_ * 128 * 1536;

    // double-buffered score phase: wave wv owns keys [wv*128, wv*128+128)
    auto LOADT = [&](int T0, short8& h0, short8& m0v, short8& l0v,
                     short8& h1, short8& m1v, short8& l1v) {
        const unsigned short* t0 = kfb + (size_t)T0 * 1536 + lane * 8;
        h0  = *(const short8*)(t0);
        m0v = *(const short8*)(t0 + 512);
        l0v = *(const short8*)(t0 + 1024);
        h1  = *(const short8*)(t0 + 1536);
        m1v = *(const short8*)(t0 + 2048);
        l1v = *(const short8*)(t0 + 2560);
    };
    auto COMPUTE = [&](const short8& bh0, const short8& bm0, const short8& bl0,
                       const short8& bh1, const short8& bm1, const short8& bl1, int p) {
        f32x4 acc0 = {0.f, 0.f, 0.f, 0.f};
        f32x4 acc1 = {0.f, 0.f, 0.f, 0.f};
        __builtin_amdgcn_s_setprio(1);
        acc0 = __builtin_amdgcn_mfma_f32_16x16x32_bf16(ah, bh0, acc0, 0, 0, 0);
        acc1 = __builtin_amdgcn_mfma_f32_16x16x32_bf16(ah, bh1, acc1, 0, 0, 0);
        acc0 = __builtin_amdgcn_mfma_f32_16x16x32_bf16(ah, bm0, acc0, 0, 0, 0);
        acc1 = __builtin_amdgcn_mfma_f32_16x16x32_bf16(ah, bm1, acc1, 0, 0, 0);
        acc0 = __builtin_amdgcn_mfma_f32_16x16x32_bf16(am, bh0, acc0, 0, 0, 0);
        acc1 = __builtin_amdgcn_mfma_f32_16x16x32_bf16(am, bh1, acc1, 0, 0, 0);
        acc0 = __builtin_amdgcn_mfma_f32_16x16x32_bf16(am, bm0, acc0, 0, 0, 0);
        acc1 = __builtin_amdgcn_mfma_f32_16x16x32_bf16(am, bm1, acc1, 0, 0, 0);
        acc0 = __builtin_amdgcn_mfma_f32_16x16x32_bf16(ah, bl0, acc0, 0, 0, 0);
        acc1 = __builtin_amdgcn_mfma_f32_16x16x32_bf16(ah, bl1, acc1, 0, 0, 0);
        acc0 = __builtin_amdgcn_mfma_f32_16x16x32_bf16(al, bh0, acc0, 0, 0, 0);
        acc1 = __builtin_amdgcn_mfma_f32_16x16x32_bf16(al, bh1, acc1, 0, 0, 0);
        __builtin_amdgcn_s_setprio(0);
        const int kc0 = wv * 128 + p * 32 + l15;
#pragma unroll
        for (int r = 0; r < 4; ++r) {
            sclds[l4 * 4 + r][kc0]      = acc0[r];
            sclds[l4 * 4 + r][kc0 + 16] = acc1[r];
        }
    };

    {
        short8 xh0, xm0, xl0, xh1, xm1, xl1;
        short8 yh0, ym0, yl0, yh1, ym1, yl1;
        LOADT(wv * 8 + 0, xh0, xm0, xl0, xh1, xm1, xl1);
        LOADT(wv * 8 + 2, yh0, ym0, yl0, yh1, ym1, yl1);
        COMPUTE(xh0, xm0, xl0, xh1, xm1, xl1, 0);
        LOADT(wv * 8 + 4, xh0, xm0, xl0, xh1, xm1, xl1);
        COMPUTE(yh0, ym0, yl0, yh1, ym1, yl1, 1);
        LOADT(wv * 8 + 6, yh0, ym0, yl0, yh1, ym1, yl1);
        COMPUTE(xh0, xm0, xl0, xh1, xm1, xl1, 2);
        COMPUTE(yh0, ym0, yl0, yh1, ym1, yl1, 3);
    }

    __syncthreads();

    const unsigned long long lanelt = (1ull << lane) - 1ull;
    {
        const int r = wv;   // one row per wave

        unsigned int u[32];
#pragma unroll
        for (int j = 0; j < 32; ++j) {
            unsigned int bb  = __float_as_uint(sclds[r][j * 64 + lane]);
            unsigned int sgn = (unsigned int)(((int)bb) >> 31);
            u[j] = bb ^ (sgn | 0x80000000u);
        }

        unsigned int lmax = u[0];
#pragma unroll
        for (int j = 1; j < 32; ++j) lmax = lmax > u[j] ? lmax : u[j];
        unsigned int umx = lmax;
#pragma unroll
        for (int off = 32; off >= 1; off >>= 1) {
            unsigned int o = (unsigned int)__shfl_xor((int)umx, off, 64);
            umx = umx > o ? umx : o;
        }
        const float mx = inv_sortable(umx);

        unsigned int PM = 0;
        for (int bit = 31; bit >= 0; --bit) {
            unsigned int test = PM | (1u << bit);
            int c2 = (int)__popcll(__ballot(lmax >= test));
            if (c2 >= TOPK) {
                PM = test;
                if (c2 == TOPK) break;
            }
        }

        int cbase = 0;
#pragma unroll
        for (int j = 0; j < 32; ++j) {
            bool alive = (u[j] >= PM);
            unsigned long long m = __ballot(alive);
            if (alive) {
                int pos = cbase + (int)__popcll(m & lanelt);
                if (pos < 128) {
                    sclds[r][1024 + pos] = __uint_as_float(u[j]);
                    sclds[r][1280 + pos] = __uint_as_float((unsigned int)(j * 64 + lane));
                }
            }
            cbase += (int)__popcll(m);
        }
        const int Ncand = cbase;

        float dsum = 0.f;
        int   base = 0;

        if (Ncand <= 128) {
            const bool v0 = lane < Ncand;
            const bool v1 = 64 + lane < Ncand;
            const unsigned int c0 = v0 ? __float_as_uint(sclds[r][1024 + lane])      : 0u;
            const unsigned int c1 = v1 ? __float_as_uint(sclds[r][1024 + 64 + lane]) : 0u;
            const unsigned int i0 = v0 ? __float_as_uint(sclds[r][1280 + lane])      : 0u;
            const unsigned int i1 = v1 ? __float_as_uint(sclds[r][1280 + 64 + lane]) : 0u;

            unsigned int P = 0;
            for (int bit = 31; bit >= 0; --bit) {
                unsigned int test = P | (1u << bit);
                int c2 = (int)__popcll(__ballot(v0 && c0 >= test))
                       + (int)__popcll(__ballot(v1 && c1 >= test));
                if (c2 >= TOPK) {
                    P = test;
                    if (c2 == TOPK) break;
                }
            }

            {
                bool sel = v0 && (c0 >= P);
                unsigned long long m = __ballot(sel);
                if (sel) {
                    float e = __expf(inv_sortable(c0) - mx);
                    int pos = (int)__popcll(m & lanelt);
                    if (pos < SELCAP) {
                        sclds[r][pos]       = e;
                        sclds[r][512 + pos] = __uint_as_float(i0);
                    }
                    dsum += e;
                }
                base = (int)__popcll(m);
            }
            {
                bool sel = v1 && (c1 >= P);
                unsigned long long m = __ballot(sel);
                if (sel) {
                    float e = __expf(inv_sortable(c1) - mx);
                    int pos = base + (int)__popcll(m & lanelt);
                    if (pos < SELCAP) {
                        sclds[r][pos]       = e;
                        sclds[r][512 + pos] = __uint_as_float(i1);
                    }
                    dsum += e;
                }
                base += (int)__popcll(m);
            }
        } else {
            unsigned int P = 0;
            for (int bit = 31; bit >= 0; --bit) {
                unsigned int test = P | (1u << bit);
                int c2 = 0;
#pragma unroll
                for (int j = 0; j < 32; ++j)
                    c2 += (int)__popcll(__ballot(u[j] >= test));
                if (c2 >= TOPK) {
                    P = test;
                    if (c2 == TOPK) break;
                }
            }
#pragma unroll
            for (int j = 0; j < 32; ++j) {
                bool sel = (u[j] >= P);
                unsigned long long m = __ballot(sel);
                if (sel) {
                    float e = __expf(inv_sortable(u[j]) - mx);
                    int pos = base + (int)__popcll(m & lanelt);
                    if (pos < SELCAP) {
                        sclds[r][pos]       = e;
                        sclds[r][512 + pos] = __uint_as_float((unsigned int)(j * 64 + lane));
                    }
                    dsum += e;
                }
                base += (int)__popcll(m);
            }
        }
#pragma unroll
        for (int off = 32; off >= 1; off >>= 1)
            dsum += __shfl_xor(dsum, off, 64);

        // ---- PV gather, 8-deep ILP ----
        const int cn = base < SELCAP ? base : SELCAP;
        const float inv = 1.0f / dsum;
        const float* vb = Vp + (size_t)b * S * DM + h * DH + lane;

        float a0 = 0.f, a1 = 0.f, a2 = 0.f, a3 = 0.f;
        float a4 = 0.f, a5 = 0.f, a6 = 0.f, a7 = 0.f;
        int tt = 0;
        for (; tt + 8 <= cn; tt += 8) {
            int   s0 = (int)__float_as_uint(sclds[r][512 + tt + 0]);
            int   s1 = (int)__float_as_uint(sclds[r][512 + tt + 1]);
            int   s2 = (int)__float_as_uint(sclds[r][512 + tt + 2]);
            int   s3 = (int)__float_as_uint(sclds[r][512 + tt + 3]);
            int   s4 = (int)__float_as_uint(sclds[r][512 + tt + 4]);
            int   s5 = (int)__float_as_uint(sclds[r][512 + tt + 5]);
            int   s6 = (int)__float_as_uint(sclds[r][512 + tt + 6]);
            int   s7 = (int)__float_as_uint(sclds[r][512 + tt + 7]);
            float w0 = sclds[r][tt + 0], w1 = sclds[r][tt + 1];
            float w2 = sclds[r][tt + 2], w3 = sclds[r][tt + 3];
            float w4 = sclds[r][tt + 4], w5 = sclds[r][tt + 5];
            float w6 = sclds[r][tt + 6], w7 = sclds[r][tt + 7];
            a0 = fmaf(w0, vb[(size_t)s0 * DM], a0);
            a1 = fmaf(w1, vb[(size_t)s1 * DM], a1);
            a2 = fmaf(w2, vb[(size_t)s2 * DM], a2);
            a3 = fmaf(w3, vb[(size_t)s3 * DM], a3);
            a4 = fmaf(w4, vb[(size_t)s4 * DM], a4);
            a5 = fmaf(w5, vb[(size_t)s5 * DM], a5);
            a6 = fmaf(w6, vb[(size_t)s6 * DM], a6);
            a7 = fmaf(w7, vb[(size_t)s7 * DM], a7);
        }
        for (; tt < cn; ++tt) {
            int s0 = (int)__float_as_uint(sclds[r][512 + tt]);
            a0 = fmaf(sclds[r][tt], vb[(size_t)s0 * DM], a0);
        }
        Oh[(size_t)(b * L + lbase + r) * DM + h * DH + lane] =
            (((a0 + a1) + (a2 + a3)) + ((a4 + a5) + (a6 + a7))) * inv;
    }
}

// ---------------------------------------------------------------------------
extern "C" void kernel_launch(void* const* d_in, const int* in_sizes, int n_in,
                              void* d_out, int out_size, void* d_ws, size_t ws_size,
                              hipStream_t stream)
{
    const float* q  = (const float*)d_in[0];
    const float* k  = (const float*)d_in[1];
    const float* v  = (const float*)d_in[2];
    const float* Wq = (const float*)d_in[3];
    const float* bq = (const float*)d_in[4];
    const float* Wk = (const float*)d_in[5];
    const float* bk = (const float*)d_in[6];
    const float* Wv = (const float*)d_in[7];
    const float* bv = (const float*)d_in[8];
    const float* Wo = (const float*)d_in[9];
    const float* bo = (const float*)d_in[10];
    // d_in[11] = pos_bias: per-head additive constant -> top-k/softmax invariant -> no-op.

    float* out = (float*)d_out;
    char*  ws  = (char*)d_ws;

    const size_t MB = 1024 * 1024;
    float*          Qp = (float*)(ws);                       //  0-8 MiB
    unsigned short* Kf = (unsigned short*)(ws + 8 * MB);     //  8-20 MiB (fragment-ordered)
    float*          Vp = (float*)(ws + 20 * MB);             // 20-36
    float*          Oh = (float*)(ws + 36 * MB);             // 36-52
    unsigned short* WvH = (unsigned short*)(ws + 36 * MB);   // overlaps Oh head (dead until attn)
    unsigned short* WvL = (unsigned short*)(ws + 38 * MB);
    unsigned short* WoH = (unsigned short*)(ws + 52 * MB);   // 52-54
    unsigned short* WoL = (unsigned short*)(ws + 54 * MB);   // 54-56

    const int M = B * L;  // 4096
    dim3 blk(256);

    transpose_split_dual<<<dim3(DM / 32, DM / 32, 2), blk, 0, stream>>>(
        Wv, WvH, WvL, Wo, WoH, WoL, DM, DM);

    gemm_mfma_split<<<dim3(DM / 128, M / 128), blk, 0, stream>>>(v, WvH, WvL, bv, Vp, M, DM, DM);

    qk_proj<<<dim3((H * R) / 128, M / 128, 2), blk, 0, stream>>>(
        q, Wq, bq, Qp, k, Wk, bk, Kf, M, H * R, DM);

    score_select_gather<<<dim3(4096), dim3(1024), 0, stream>>>(Qp, Kf, Vp, Oh);

    gemm_mfma_split<<<dim3(DM / 128, M / 128), blk, 0, stream>>>(Oh, WoH, WoL, bo, out, M, DM, DM);
}